// Round 10
// baseline (1099.883 us; speedup 1.0000x reference)
//
#include <hip/hip_runtime.h>
#include <cstdint>
#include <cstddef>

typedef unsigned short u16;
typedef __attribute__((ext_vector_type(8))) short bf16x8;
typedef __attribute__((ext_vector_type(4))) float f32x4;

#define TS 520          // padded tile stride (u16): 64 x-cols + 8 pad, 16B-aligned
#define RB 33280        // region B offset (64*TS)
#define PB 66560        // P-scratch offset (8 waves x 512)

__device__ __forceinline__ float bf2f(u16 u) {
  return __uint_as_float(((unsigned)u) << 16);
}
__device__ __forceinline__ u16 f2bf(float f) {
  unsigned x = __float_as_uint(f);
  return (u16)((x + 0x7fffu + ((x >> 16) & 1u)) >> 16);
}
// packed RNE f32x2 -> bf16x2 (gfx950): low16 = a, high16 = b
__device__ __forceinline__ unsigned pk2(float a, float b) {
  unsigned r;
  asm("v_cvt_pk_bf16_f32 %0, %1, %2" : "=v"(r) : "v"(a), "v"(b));
  return r;
}
__device__ __forceinline__ float pkget(unsigned u, int hi) {
  return bf2f((u16)(hi ? (u >> 16) : (u & 0xffffu)));
}

// swizzle for tile (g, dl): spreads both b128 x-run reads (dl varies) and
// cross-tile scatter writes (g varies) across banks.
__device__ __forceinline__ int sw(int g, int dl) {
  return (((g >> 3) ^ g ^ dl) & 7) << 3;
}
// region tile addressing: tile g, d-row dl (0..7), x-col (0..63)
__device__ __forceinline__ int taddr(int base, int g, int dl, int x) {
  return base + g * TS + (dl << 6) + (x ^ sw(g, dl));
}
// B-fragment from a tile: col c=lane&15 (clamped &7), k-run over x
__device__ __forceinline__ bf16x8 tfrag(const ushort* Xs, int base, int g, int ks, int l) {
  const int c = l & 7;
  const int x = ((ks << 2) + (l >> 4)) << 3;
  return *(const bf16x8*)&Xs[base + g * TS + (c << 6) + (x ^ sw(g, c))];
}
// wave-private P scratch
__device__ __forceinline__ int paddr(int w, int dl, int y) {
  return PB + (w << 9) + (dl << 6) + (y ^ ((dl & 7) << 3));
}
__device__ __forceinline__ bf16x8 pfrag(const ushort* Xs, int w, int ks, int l) {
  const int c = l & 7;
  const int x = ((ks << 2) + (l >> 4)) << 3;
  return *(const bf16x8*)&Xs[PB + (w << 9) + (c << 6) + (x ^ ((c & 7) << 3))];
}

// pre-packed bf16 weight fragment: flat row = gr*16 + (lane&15), k = ks*32 + (lane>>4)*8 + e
__device__ __forceinline__ bf16x8 apk_frag(const u16* __restrict__ APK, int mat, int gr,
                                           int ks, int lane) {
  return *(const bf16x8*)&APK[(((((mat << 8) + gr) << 1) + ks) << 9) + lane * 8];
}
// acc[grp] rows = grp*16 + (lane>>4)*4 + r (weight flat-row), cols = lane&15 (d)
__device__ __forceinline__ void wmm(const u16* __restrict__ APK, int mat, int unit,
                                    bf16x8 f0, bf16x8 f1, int lane, f32x4 acc[4]) {
#pragma unroll
  for (int grp = 0; grp < 4; ++grp) {
    acc[grp] = __builtin_amdgcn_mfma_f32_16x16x32_bf16(
        apk_frag(APK, mat, unit * 4 + grp, 0, lane), f0, acc[grp], 0, 0, 0);
    acc[grp] = __builtin_amdgcn_mfma_f32_16x16x32_bf16(
        apk_frag(APK, mat, unit * 4 + grp, 1, lane), f1, acc[grp], 0, 0, 0);
  }
}

// ---------------------------------------------------------------------------
// k_prep: pack {M1L,M1R,M2L,M2R} into fragment order bf16 (2 MB, in d_ws).
// mat 0 packs k-slot kk <- W[row][((kk&7)<<3)|(kk>>3)] (stage-in xpos involution).
// ---------------------------------------------------------------------------
__global__ __launch_bounds__(256) void k_prep(const float* __restrict__ W0,
                                              const float* __restrict__ W1,
                                              const float* __restrict__ W2,
                                              const float* __restrict__ W3,
                                              u16* __restrict__ APK) {
  const int gr = blockIdx.x, mat = blockIdx.y;
  const float* W = (mat == 0) ? W0 : (mat == 1) ? W1 : (mat == 2) ? W2 : W3;
  const int t = threadIdx.x;
  const int lane = t & 63, ks = (t >> 6) & 1, half = t >> 7;
  const int row = gr * 16 + (lane & 15);
  const int k0 = ks * 32 + ((lane >> 4) << 3) + half * 4;
  ushort4 o;
  if (mat == 0) {
    o.x = f2bf(W[row * 64 + ((((k0 + 0) & 7) << 3) | ((k0 + 0) >> 3))]);
    o.y = f2bf(W[row * 64 + ((((k0 + 1) & 7) << 3) | ((k0 + 1) >> 3))]);
    o.z = f2bf(W[row * 64 + ((((k0 + 2) & 7) << 3) | ((k0 + 2) >> 3))]);
    o.w = f2bf(W[row * 64 + ((((k0 + 3) & 7) << 3) | ((k0 + 3) >> 3))]);
  } else {
    float4 v = *(const float4*)&W[row * 64 + k0];
    o.x = f2bf(v.x); o.y = f2bf(v.y); o.z = f2bf(v.z); o.w = f2bf(v.w);
  }
  *(ushort4*)&APK[((((((mat << 8) + gr) << 1) + ks) << 6) + lane) * 8 + half * 4] = o;
}

// ---------------------------------------------------------------------------
// k_mega v5: fused 4-stage monarch chain, ping-pong LDS regions, d-octet split.
// 512 threads (8 waves), 138 KiB LDS, grid 256 (1 block/CU).
// No register tile-cache (no in-place hazard) -> demand ~85 VGPR, no spill.
// ---------------------------------------------------------------------------
__global__ __launch_bounds__(512) void k_mega(const float* __restrict__ q,
                                              const float* __restrict__ keys,
                                              const float* __restrict__ vals,
                                              const u16* __restrict__ APK,
                                              const float* __restrict__ b1,
                                              const float* __restrict__ b2,
                                              float* __restrict__ out) {
  __shared__ ushort Xs[70656];  // 138 KiB: regionA 65K + regionB 65K + P 8K
  const int bid = blockIdx.x;
  const int dq = bid >> 6;
  const int bh = bid & 63;
  const int b = bh >> 3, h = bh & 7;
  const int tid = threadIdx.x, w = tid >> 6, l = tid & 63;
  const int c = l & 15;           // MFMA C-column for this lane
  const bool cok = c < 8;         // active half (d-octet)
  const size_t inbase = (size_t)b * 4096 * 512 + h * 64 + dq * 16;  // + s*512 + d

  for (int oct = 0; oct < 2; ++oct) {
    const size_t obase = inbase + oct * 8;

    // ---- stage-in: q -> region A; tile g = l holds [dl][xpos], xpos = ((m&7)<<3)|(m>>3)
#pragma unroll
    for (int hq = 0; hq < 2; ++hq) {
      float st[4][8];
#pragma unroll
      for (int j4 = 0; j4 < 4; ++j4) {
        const int m = ((hq << 2) + j4) * 8 + w;
        const float* qr = q + obase + (size_t)(m * 64 + l) * 512;
        float4 v0 = *(const float4*)(qr);
        float4 v1 = *(const float4*)(qr + 4);
        st[j4][0] = v0.x; st[j4][1] = v0.y; st[j4][2] = v0.z; st[j4][3] = v0.w;
        st[j4][4] = v1.x; st[j4][5] = v1.y; st[j4][6] = v1.z; st[j4][7] = v1.w;
      }
      const int x0 = (w << 3) | (hq << 2);
#pragma unroll
      for (int d8 = 0; d8 < 8; ++d8) {
        uint2 pw;
        pw.x = pk2(st[0][d8], st[1][d8]);
        pw.y = pk2(st[2][d8], st[3][d8]);
        *(uint2*)&Xs[taddr(0, l, d8, x0)] = pw;
      }
    }
    __syncthreads();

    // ---- S1: A -> B.  T1[(n,B)] = sum_m L1[B][n][m] q[(m,B)]; write tile n, x=B
#pragma unroll
    for (int u = 0; u < 8; ++u) {
      const int g = w * 8 + u;
      bf16x8 f0 = tfrag(Xs, 0, g, 0, l);
      bf16x8 f1 = tfrag(Xs, 0, g, 1, l);
      f32x4 acc[4] = {};
      wmm(APK, 0, g, f0, f1, l, acc);
      if (cok) {
#pragma unroll
        for (int grp = 0; grp < 4; ++grp)
#pragma unroll
          for (int r = 0; r < 4; ++r) {
            const int n = (grp << 4) + ((l >> 4) << 2) + r;
            Xs[taddr(RB, n, c, g)] = f2bf(acc[grp][r]);
          }
      }
    }
    __syncthreads();

    // ---- S2+S3: B -> (P) -> A.  P=(R1[n]·T1)∘k+b1; T2=L2[n]·P; write tile n2, x=n
#pragma unroll
    for (int u = 0; u < 8; ++u) {
      const int n = w * 8 + u;
      unsigned kpk[8], bpk[8];
      if (cok) {
#pragma unroll
        for (int grp = 0; grp < 4; ++grp) {
          float kt[4], bt[4];
#pragma unroll
          for (int r = 0; r < 4; ++r) {
            const int y = (grp << 4) + ((l >> 4) << 2) + r;
            kt[r] = keys[obase + (size_t)((y << 6) + n) * 512 + c];
            bt[r] = b1[(y << 6) + n];
          }
          kpk[grp * 2] = pk2(kt[0], kt[1]); kpk[grp * 2 + 1] = pk2(kt[2], kt[3]);
          bpk[grp * 2] = pk2(bt[0], bt[1]); bpk[grp * 2 + 1] = pk2(bt[2], bt[3]);
        }
      }
      bf16x8 f0 = tfrag(Xs, RB, n, 0, l);
      bf16x8 f1 = tfrag(Xs, RB, n, 1, l);
      f32x4 acc[4] = {};
      wmm(APK, 1, n, f0, f1, l, acc);
      if (cok) {
#pragma unroll
        for (int grp = 0; grp < 4; ++grp)
#pragma unroll
          for (int r = 0; r < 4; ++r) {
            const int y = (grp << 4) + ((l >> 4) << 2) + r;
            const float kf = pkget(kpk[grp * 2 + (r >> 1)], r & 1);
            const float bf = pkget(bpk[grp * 2 + (r >> 1)], r & 1);
            Xs[paddr(w, c, y)] = f2bf(acc[grp][r] * kf + bf);
          }
      }
      bf16x8 s0 = pfrag(Xs, w, 0, l);
      bf16x8 s1 = pfrag(Xs, w, 1, l);
      f32x4 acc2[4] = {};
      wmm(APK, 2, n, s0, s1, l, acc2);
      if (cok) {
#pragma unroll
        for (int grp = 0; grp < 4; ++grp)
#pragma unroll
          for (int r = 0; r < 4; ++r) {
            const int n2 = (grp << 4) + ((l >> 4) << 2) + r;
            Xs[taddr(0, n2, c, n)] = f2bf(acc2[grp][r]);
          }
      }
    }
    __syncthreads();

    // ---- S4: A -> B.  Y = (R2[n2]·T2 + b2)∘v; write tile i2, x=n2
#pragma unroll
    for (int u = 0; u < 8; ++u) {
      const int n2 = w * 8 + u;
      unsigned vpk[8], bpk[8];
      if (cok) {
#pragma unroll
        for (int grp = 0; grp < 4; ++grp) {
          float vt[4], bt[4];
#pragma unroll
          for (int r = 0; r < 4; ++r) {
            const int i2 = (grp << 4) + ((l >> 4) << 2) + r;
            vt[r] = vals[obase + (size_t)((i2 << 6) + n2) * 512 + c];
            bt[r] = b2[(i2 << 6) + n2];
          }
          vpk[grp * 2] = pk2(vt[0], vt[1]); vpk[grp * 2 + 1] = pk2(vt[2], vt[3]);
          bpk[grp * 2] = pk2(bt[0], bt[1]); bpk[grp * 2 + 1] = pk2(bt[2], bt[3]);
        }
      }
      bf16x8 f0 = tfrag(Xs, 0, n2, 0, l);
      bf16x8 f1 = tfrag(Xs, 0, n2, 1, l);
      f32x4 acc[4] = {};
      wmm(APK, 3, n2, f0, f1, l, acc);
      if (cok) {
#pragma unroll
        for (int grp = 0; grp < 4; ++grp)
#pragma unroll
          for (int r = 0; r < 4; ++r) {
            const int i2 = (grp << 4) + ((l >> 4) << 2) + r;
            const float vf = pkget(vpk[grp * 2 + (r >> 1)], r & 1);
            const float bf = pkget(bpk[grp * 2 + (r >> 1)], r & 1);
            Xs[taddr(RB, i2, c, n2)] = f2bf((acc[grp][r] + bf) * vf);
          }
      }
    }
    __syncthreads();

    // ---- out: region B -> out[bh][d][s] fp32, coalesced; wave w owns d-row w.
    // Overlaps the next octet's stage-in (different region), so no barrier after.
    {
      float* orow = out + ((size_t)bh * 64 + (dq << 4) + (oct << 3) + w) * 4096;
#pragma unroll
      for (int o = 0; o < 16; ++o) {
        const int s4 = (o << 8) + (l << 2);
        uint2 rv = *(const uint2*)&Xs[taddr(RB, s4 >> 6, w, s4 & 63)];
        float4 ov;
        ov.x = bf2f((u16)(rv.x & 0xffffu));
        ov.y = bf2f((u16)(rv.x >> 16));
        ov.z = bf2f((u16)(rv.y & 0xffffu));
        ov.w = bf2f((u16)(rv.y >> 16));
        *(float4*)(orow + s4) = ov;
      }
    }
  }
}

// ---------------------------------------------------------------------------
extern "C" void kernel_launch(void* const* d_in, const int* in_sizes, int n_in,
                              void* d_out, int out_size, void* d_ws, size_t ws_size,
                              hipStream_t stream) {
  const float* q   = (const float*)d_in[0];
  const float* k   = (const float*)d_in[1];
  const float* v   = (const float*)d_in[2];
  const float* M1L = (const float*)d_in[3];
  const float* M1R = (const float*)d_in[4];
  const float* M2L = (const float*)d_in[5];
  const float* M2R = (const float*)d_in[6];
  const float* b1  = (const float*)d_in[7];
  const float* b2  = (const float*)d_in[8];

  u16* APK = (u16*)d_ws;  // 2 MB packed weights

  k_prep<<<dim3(256, 4), 256, 0, stream>>>(M1L, M1R, M2L, M2R, APK);
  k_mega<<<256, 512, 0, stream>>>(q, k, v, APK, b1, b2, (float*)d_out);
}

// Round 11
// 115.592 us; speedup vs baseline: 9.5152x; 9.5152x over previous
//
#include <hip/hip_runtime.h>
#include <cstdint>
#include <cstddef>

typedef unsigned short u16;
typedef __attribute__((ext_vector_type(8))) short bf16x8;
typedef __attribute__((ext_vector_type(4))) float f32x4;

#define S_LEN 4096

__device__ __forceinline__ float bf2f(u16 u) {
  return __uint_as_float(((unsigned)u) << 16);
}
__device__ __forceinline__ u16 f2bf(float f) {
  unsigned x = __float_as_uint(f);
  return (u16)((x + 0x7fffu + ((x >> 16) & 1u)) >> 16);
}

// XOR-swizzled 64x64 u16 LDS tile: logical (c=col, r=row), row = contraction.
__device__ __forceinline__ int ltelem(int c, int r) {
  int swz = ((r >> 3) ^ (c & 7) ^ ((c >> 3) & 7)) & 7;
  return (c << 6) | (swz << 3) | (r & 7);
}

// Tile fragment (MFMA A operand): row = a*16 + (lane&15) over tile col dim c,
// k-run = (ks*4 + lane>>4)*8 over tile row dim r.
__device__ __forceinline__ bf16x8 tile_frag(const ushort* LT, int a, int ks, int lane) {
  int c = (a << 4) + (lane & 15);
  int kg = (ks << 2) + (lane >> 4);
  int base = (c << 6) | (((kg ^ (c & 7) ^ ((c >> 3) & 7)) & 7) << 3);
  return *(const bf16x8*)&LT[base];
}

// Pre-packed bf16 weight fragment (MFMA B operand):
// col = gr*16 + (lane&15) (flat weight row), k = ks*32 + (lane>>4)*8 + e.
__device__ __forceinline__ bf16x8 apk_frag(const u16* __restrict__ APK, int mat, int gr,
                                           int ks, int lane) {
  return *(const bf16x8*)&APK[(((((mat << 8) + gr) << 1) + ks) << 9) + lane * 8];
}

// One wave: C[d=64 rows][16 cols] — transposed orientation.
// acc[a]: rows d = a*16 + (lane>>4)*4 + reg (4 CONSECUTIVE d per lane),
//         col  = gr*16 + (lane&15).
__device__ __forceinline__ void mmT(const ushort* LT, const u16* __restrict__ APK,
                                    int mat, int gr, int lane, f32x4 acc[4]) {
#pragma unroll
  for (int ks = 0; ks < 2; ++ks) {
    bf16x8 bw = apk_frag(APK, mat, gr, ks, lane);
#pragma unroll
    for (int a = 0; a < 4; ++a) {
      bf16x8 at = tile_frag(LT, a, ks, lane);
      acc[a] = __builtin_amdgcn_mfma_f32_16x16x32_bf16(at, bw, acc[a], 0, 0, 0);
    }
  }
}

// ---------------------------------------------------------------------------
// k_prep: pack {M1L,M1R,M2L,M2R} (fp32 64^3 row-major) into fragment order bf16.
// grid (gr=256, mat=4), 256 thr.
// ---------------------------------------------------------------------------
__global__ __launch_bounds__(256) void k_prep(const float* __restrict__ W0,
                                              const float* __restrict__ W1,
                                              const float* __restrict__ W2,
                                              const float* __restrict__ W3,
                                              u16* __restrict__ APK) {
  const int gr = blockIdx.x, mat = blockIdx.y;
  const float* W = (mat == 0) ? W0 : (mat == 1) ? W1 : (mat == 2) ? W2 : W3;
  const int t = threadIdx.x;
  const int lane = t & 63, ks = (t >> 6) & 1, half = t >> 7;
  const int row = gr * 16 + (lane & 15);
  const int k0 = ks * 32 + ((lane >> 4) << 3) + half * 4;
  float4 v = *(const float4*)&W[row * 64 + k0];
  ushort4 o;
  o.x = f2bf(v.x); o.y = f2bf(v.y); o.z = f2bf(v.z); o.w = f2bf(v.w);
  *(ushort4*)&APK[((((((mat << 8) + gr) << 1) + ks) << 6) + lane) * 8 + half * 4] = o;
}

// ---------------------------------------------------------------------------
// K1: T1[bh][n][B][d] = sum_m L1[B][n][m] * q[b, m*64+B, h, d]   (bf16 out)
// grid (B0=16, bh=64): 4 consecutive B per block, double-buffered staging.
// ---------------------------------------------------------------------------
__global__ __launch_bounds__(256) void k_m1(const float* __restrict__ q,
                                            const u16* __restrict__ APK,
                                            u16* __restrict__ T1) {
  const int B0 = blockIdx.x << 2, bh = blockIdx.y;
  const int b = bh >> 3, h = bh & 7;
  __shared__ ushort LT[2][4096];          // (c=d, r=m)
  const int tid = threadIdx.x, w = tid >> 6, lane = tid & 63;
  const int m = tid >> 2, ch = tid & 3;
  const int nrow = (w << 4) + (lane & 15);
  const int dg = (lane >> 4) << 2;

  float4 c0, c1, c2, c3;
  {
    const float* qr = q + ((((size_t)b * S_LEN + (size_t)m * 64 + B0) * 8 + h) << 6) + ch * 16;
    c0 = ((const float4*)qr)[0]; c1 = ((const float4*)qr)[1];
    c2 = ((const float4*)qr)[2]; c3 = ((const float4*)qr)[3];
  }
#pragma unroll
  for (int i = 0; i < 4; ++i) {
    const int B = B0 + i;
    {
      float fl[16] = {c0.x, c0.y, c0.z, c0.w, c1.x, c1.y, c1.z, c1.w,
                      c2.x, c2.y, c2.z, c2.w, c3.x, c3.y, c3.z, c3.w};
      const int cc = ch * 16;
#pragma unroll
      for (int e = 0; e < 16; ++e) LT[i & 1][ltelem(cc + e, m)] = f2bf(fl[e]);
    }
    float4 p0 = {}, p1 = {}, p2 = {}, p3 = {};
    if (i < 3) {
      const float* qr = q + ((((size_t)b * S_LEN + (size_t)m * 64 + B + 1) * 8 + h) << 6) + ch * 16;
      p0 = ((const float4*)qr)[0]; p1 = ((const float4*)qr)[1];
      p2 = ((const float4*)qr)[2]; p3 = ((const float4*)qr)[3];
    }
    __syncthreads();
    f32x4 acc[4] = {};
    mmT(LT[i & 1], APK, 0, B * 4 + w, lane, acc);
#pragma unroll
    for (int a = 0; a < 4; ++a) {
      int d0 = (a << 4) + dg;
      ushort4 o;
      o.x = f2bf(acc[a][0]); o.y = f2bf(acc[a][1]);
      o.z = f2bf(acc[a][2]); o.w = f2bf(acc[a][3]);
      *(ushort4*)&T1[(((size_t)bh * 64 + nrow) * 64 + B) * 64 + d0] = o;
    }
    c0 = p0; c1 = p1; c2 = p2; c3 = p3;
  }
}

// ---------------------------------------------------------------------------
// K2: per (bh, n):  mm(R1) -> *k + b1 -> mm(L2) -> T2[bh][n'][n][d]
// grid (n0=16, bh=64): 4 n per block, double-buffered T1 staging + keys prefetch.
// ---------------------------------------------------------------------------
__global__ __launch_bounds__(256) void k_m2b(const u16* __restrict__ T1,
                                             const u16* __restrict__ APK,
                                             const float* __restrict__ keys,
                                             const float* __restrict__ b1,
                                             u16* __restrict__ T2) {
  const int n0 = blockIdx.x << 2, bh = blockIdx.y;
  const int b = bh >> 3, h = bh & 7;
  __shared__ ushort LT[2][4096];   // T1 tile, (c=d, r=B)
  __shared__ ushort LT2[4096];     // A tile,  (c=d, r=p)
  const int tid = threadIdx.x, w = tid >> 6, lane = tid & 63;
  const int p = (w << 4) + (lane & 15);
  const int dg = (lane >> 4) << 2;
  const int rowi = tid >> 2, ch = tid & 3;

  uint4 ct0, ct1;
  float4 ck[4];
  float cb;
  {
    const u16* src = T1 + (((size_t)bh * 64 + n0) * 64 + rowi) * 64 + ch * 16;
    ct0 = *(const uint4*)(src);
    ct1 = *(const uint4*)(src + 8);
    const float* krow = &keys[(((size_t)b * S_LEN + p * 64 + n0) * 8 + h) << 6];
#pragma unroll
    for (int a = 0; a < 4; ++a) ck[a] = *(const float4*)(krow + (a << 4) + dg);
    cb = b1[p * 64 + n0];
  }
#pragma unroll
  for (int i = 0; i < 4; ++i) {
    const int n = n0 + i;
    {
      u16 buf[16];
      *(uint4*)&buf[0] = ct0; *(uint4*)&buf[8] = ct1;
      const int cc = ch * 16;
#pragma unroll
      for (int e = 0; e < 16; ++e) LT[i & 1][ltelem(cc + e, rowi)] = buf[e];
    }
    uint4 pt0 = {}, pt1 = {};
    float4 pk[4] = {};
    float pb = 0.f;
    if (i < 3) {
      const u16* src = T1 + (((size_t)bh * 64 + n + 1) * 64 + rowi) * 64 + ch * 16;
      pt0 = *(const uint4*)(src);
      pt1 = *(const uint4*)(src + 8);
      const float* krow = &keys[(((size_t)b * S_LEN + p * 64 + n + 1) * 8 + h) << 6];
#pragma unroll
      for (int a = 0; a < 4; ++a) pk[a] = *(const float4*)(krow + (a << 4) + dg);
      pb = b1[p * 64 + n + 1];
    }
    __syncthreads();
    f32x4 acc[4] = {};
    mmT(LT[i & 1], APK, 1, n * 4 + w, lane, acc);    // R1: C[d][p]
#pragma unroll
    for (int a = 0; a < 4; ++a) {
      int d0 = (a << 4) + dg;
      LT2[ltelem(d0 + 0, p)] = f2bf(acc[a][0] * ck[a].x + cb);
      LT2[ltelem(d0 + 1, p)] = f2bf(acc[a][1] * ck[a].y + cb);
      LT2[ltelem(d0 + 2, p)] = f2bf(acc[a][2] * ck[a].z + cb);
      LT2[ltelem(d0 + 3, p)] = f2bf(acc[a][3] * ck[a].w + cb);
    }
    __syncthreads();
    f32x4 acc2[4] = {};
    mmT(LT2, APK, 2, n * 4 + w, lane, acc2);         // L2: C[d][n2]
    const int n2 = p;
#pragma unroll
    for (int a = 0; a < 4; ++a) {
      int d0 = (a << 4) + dg;
      ushort4 o;
      o.x = f2bf(acc2[a][0]); o.y = f2bf(acc2[a][1]);
      o.z = f2bf(acc2[a][2]); o.w = f2bf(acc2[a][3]);
      *(ushort4*)&T2[(((size_t)bh * 64 + n2) * 64 + n) * 64 + d0] = o;
    }
    ct0 = pt0; ct1 = pt1; cb = pb;
#pragma unroll
    for (int a = 0; a < 4; ++a) ck[a] = pk[a];
  }
}

// ---------------------------------------------------------------------------
// K3: per (bh, n'): mm(R2) -> (+b2)*v -> Yp[bh][n'][p][d] bf16
// grid (np0=16, bh=64): 4 n' per block, double-buffered staging + vals prefetch.
// ---------------------------------------------------------------------------
__global__ __launch_bounds__(256) void k_m3b(const u16* __restrict__ T2,
                                             const u16* __restrict__ APK,
                                             const float* __restrict__ vals,
                                             const float* __restrict__ b2,
                                             u16* __restrict__ Yp) {
  const int np0 = blockIdx.x << 2, bh = blockIdx.y;
  const int b = bh >> 3, h = bh & 7;
  __shared__ ushort LT[2][4096];   // T2 tile, (c=d, r=n)
  const int tid = threadIdx.x, w = tid >> 6, lane = tid & 63;
  const int p = (w << 4) + (lane & 15);
  const int dg = (lane >> 4) << 2;
  const int rowi = tid >> 2, ch = tid & 3;

  uint4 ct0, ct1;
  float4 cv[4];
  float cb;
  {
    const u16* src = T2 + (((size_t)bh * 64 + np0) * 64 + rowi) * 64 + ch * 16;
    ct0 = *(const uint4*)(src);
    ct1 = *(const uint4*)(src + 8);
    const float* vrow = &vals[(((size_t)b * S_LEN + p * 64 + np0) * 8 + h) << 6];
#pragma unroll
    for (int a = 0; a < 4; ++a) cv[a] = *(const float4*)(vrow + (a << 4) + dg);
    cb = b2[p * 64 + np0];
  }
#pragma unroll
  for (int i = 0; i < 4; ++i) {
    const int np = np0 + i;
    {
      u16 buf[16];
      *(uint4*)&buf[0] = ct0; *(uint4*)&buf[8] = ct1;
      const int cc = ch * 16;
#pragma unroll
      for (int e = 0; e < 16; ++e) LT[i & 1][ltelem(cc + e, rowi)] = buf[e];
    }
    uint4 pt0 = {}, pt1 = {};
    float4 pv[4] = {};
    float pb = 0.f;
    if (i < 3) {
      const u16* src = T2 + (((size_t)bh * 64 + np + 1) * 64 + rowi) * 64 + ch * 16;
      pt0 = *(const uint4*)(src);
      pt1 = *(const uint4*)(src + 8);
      const float* vrow = &vals[(((size_t)b * S_LEN + p * 64 + np + 1) * 8 + h) << 6];
#pragma unroll
      for (int a = 0; a < 4; ++a) pv[a] = *(const float4*)(vrow + (a << 4) + dg);
      pb = b2[p * 64 + np + 1];
    }
    __syncthreads();
    f32x4 acc[4] = {};
    mmT(LT[i & 1], APK, 3, np * 4 + w, lane, acc);   // R2: C[d][p']
#pragma unroll
    for (int a = 0; a < 4; ++a) {
      int d0 = (a << 4) + dg;
      ushort4 o;
      o.x = f2bf((acc[a][0] + cb) * cv[a].x);
      o.y = f2bf((acc[a][1] + cb) * cv[a].y);
      o.z = f2bf((acc[a][2] + cb) * cv[a].z);
      o.w = f2bf((acc[a][3] + cb) * cv[a].w);
      *(ushort4*)&Yp[(((size_t)bh * 64 + np) * 64 + p) * 64 + d0] = o;
    }
    ct0 = pt0; ct1 = pt1; cb = pb;
#pragma unroll
    for (int a = 0; a < 4; ++a) cv[a] = pv[a];
  }
}

// ---------------------------------------------------------------------------
// K4: out[bh][d][p*64+np] = Yp[bh][np][p][d]  (fp32, coalesced both sides)
// grid (p=64, bh=64)
// ---------------------------------------------------------------------------
__global__ __launch_bounds__(256) void k_tr(const u16* __restrict__ Yp,
                                            float* __restrict__ out) {
  const int p = blockIdx.x, bh = blockIdx.y;
  __shared__ ushort YT[4096];    // (c=np, r=d)
  const int tid = threadIdx.x;
#pragma unroll
  for (int i = 0; i < 2; ++i) {
    int idx = i * 256 + tid;
    int np = idx >> 3, q8 = idx & 7;   // d0 = q8*8
    uint4 vv = *(const uint4*)&Yp[(((size_t)bh * 64 + np) * 64 + p) * 64 + q8 * 8];
    *(uint4*)&YT[ltelem(np, q8 * 8)] = vv;
  }
  __syncthreads();
#pragma unroll
  for (int i = 0; i < 4; ++i) {
    int idx = i * 256 + tid;
    int d = idx >> 4, np0 = (idx & 15) * 4;
    float4 o;
    o.x = bf2f(YT[ltelem(np0 + 0, d)]);
    o.y = bf2f(YT[ltelem(np0 + 1, d)]);
    o.z = bf2f(YT[ltelem(np0 + 2, d)]);
    o.w = bf2f(YT[ltelem(np0 + 3, d)]);
    *(float4*)&out[((size_t)bh * 64 + d) * S_LEN + p * 64 + np0] = o;
  }
}

// ---------------------------------------------------------------------------
extern "C" void kernel_launch(void* const* d_in, const int* in_sizes, int n_in,
                              void* d_out, int out_size, void* d_ws, size_t ws_size,
                              hipStream_t stream) {
  const float* q   = (const float*)d_in[0];
  const float* k   = (const float*)d_in[1];
  const float* v   = (const float*)d_in[2];
  const float* M1L = (const float*)d_in[3];
  const float* M1R = (const float*)d_in[4];
  const float* M2L = (const float*)d_in[5];
  const float* M2R = (const float*)d_in[6];
  const float* b1  = (const float*)d_in[7];
  const float* b2  = (const float*)d_in[8];

  u16* T1 = (u16*)d_ws;
  u16* T2 = T1 + (size_t)64 * 64 * 64 * 64;  // 32 MB each
  u16* Yp = T1;                              // T1 dead after K2 — reuse
  // Apack (2 MB) in the head of d_out: consumed by k_m1..k_m3b, then k_tr
  // (the final kernel) rewrites every output element. d_out is 64 MiB.
  u16* APK = (u16*)d_out;

  dim3 blk(256);
  k_prep<<<dim3(256, 4), blk, 0, stream>>>(M1L, M1R, M2L, M2R, APK);
  k_m1 <<<dim3(16, 64), blk, 0, stream>>>(q, APK, T1);
  k_m2b<<<dim3(16, 64), blk, 0, stream>>>(T1, APK, k, b1, T2);
  k_m3b<<<dim3(16, 64), blk, 0, stream>>>(T2, APK, v, b2, Yp);
  k_tr <<<dim3(64, 64), blk, 0, stream>>>(Yp, (float*)d_out);
}